// Round 1
// baseline (1104.911 us; speedup 1.0000x reference)
//
#include <hip/hip_runtime.h>
#include <cstdint>
#include <cstddef>

// ---- fixed problem shape (from setup_inputs) ------------------------------
#define E_      24          // experts
#define D_IN    1024
#define D_HID   4096
#define HGRP    4           // groups (H)
#define BSZ     4
#define SEQ     2048
#define NSUB    512         // seq / HGRP
#define S_      2048        // tokens per group = BSZ*NSUB
#define NTOKG   8192        // HGRP * S_
#define CAP     171         // ceil(2*S_/E_)
#define MR      768         // per-expert rows, 4*CAP=684 padded to 6*128
#define MT      6           // M tiles of 128

typedef __attribute__((ext_vector_type(4))) float          f32x4;
typedef __attribute__((ext_vector_type(4))) unsigned short u16x4;
typedef __attribute__((ext_vector_type(4))) unsigned int   u32x4;
typedef __attribute__((ext_vector_type(8))) short          s16x8;

__device__ __forceinline__ unsigned short f2bf(float f) {   // RNE f32->bf16
  unsigned int u = __float_as_uint(f);
  u += 0x7fffu + ((u >> 16) & 1u);
  return (unsigned short)(u >> 16);
}
__device__ __forceinline__ float bf2f(unsigned short v) {
  return __uint_as_float(((unsigned int)v) << 16);
}

// ---- 1) gating: logits = x_row @ Wg, softmax, top-2 (first-max ties) -----
__global__ __launch_bounds__(64)
void k_gating(const float* __restrict__ x, const float* __restrict__ Wg,
              int* __restrict__ tokE1, int* __restrict__ tokE2,
              float* __restrict__ tokG1, float* __restrict__ tokG2) {
  int tg = blockIdx.x;                 // h*S_ + s
  int h = tg >> 11, s = tg & 2047;
  int bi = s >> 9, ni = s & 511;
  const float* xr = x + ((size_t)bi*SEQ + (size_t)h*NSUB + ni) * D_IN;
  int lane = threadIdx.x;
  float acc[E_];
  #pragma unroll
  for (int e = 0; e < E_; ++e) acc[e] = 0.f;
  #pragma unroll
  for (int it = 0; it < D_IN/256; ++it) {
    f32x4 xv = *(const f32x4*)(xr + it*256 + lane*4);
    #pragma unroll
    for (int j = 0; j < 4; ++j) {
      float xs = xv[j];
      const float* wrow = Wg + (size_t)(it*256 + lane*4 + j) * E_;
      #pragma unroll
      for (int e = 0; e < E_; ++e) acc[e] += xs * wrow[e];
    }
  }
  #pragma unroll
  for (int e = 0; e < E_; ++e) {
    float v = acc[e];
    v += __shfl_xor(v, 32); v += __shfl_xor(v, 16); v += __shfl_xor(v, 8);
    v += __shfl_xor(v, 4);  v += __shfl_xor(v, 2);  v += __shfl_xor(v, 1);
    acc[e] = v;
  }
  if (lane == 0) {
    float mx = acc[0];
    #pragma unroll
    for (int e = 1; e < E_; ++e) mx = fmaxf(mx, acc[e]);
    float den = 0.f;
    #pragma unroll
    for (int e = 0; e < E_; ++e) den += expf(acc[e] - mx);
    int i1 = 0; float v1 = acc[0];
    #pragma unroll
    for (int e = 1; e < E_; ++e) if (acc[e] > v1) { v1 = acc[e]; i1 = e; }  // first max
    int i2 = -1; float v2 = -3.4e38f;
    #pragma unroll
    for (int e = 0; e < E_; ++e) if (e != i1 && acc[e] > v2) { v2 = acc[e]; i2 = e; }
    tokE1[tg] = i1; tokE2[tg] = i2;
    tokG1[tg] = expf(v1 - mx) / den;   // raw softmax probs; renorm after drops
    tokG2[tg] = expf(v2 - mx) / den;
  }
}

// ---- 2) slot map init ----------------------------------------------------
__global__ void k_init_slots(int* __restrict__ slotTok) {
  slotTok[blockIdx.x*256 + threadIdx.x] = -1;
}

// ---- 3) capacity scan: exact cumsum order, loc2 offset by RAW top1 totals
__global__ __launch_bounds__(64)
void k_scan(const int* __restrict__ tokE1, const int* __restrict__ tokE2,
            float* __restrict__ tokG1, float* __restrict__ tokG2,
            int* __restrict__ tokP1, int* __restrict__ tokP2,
            int* __restrict__ slotTok) {
  int h = blockIdx.x;
  int lane = threadIdx.x;
  __shared__ int cnt[64][E_];
  __shared__ int tot1[E_];
  const int CH = S_/64;                           // 32 tokens per lane chunk
  const int* e1 = tokE1 + h*S_;
  const int* e2 = tokE2 + h*S_;
  // choice 1
  #pragma unroll
  for (int e = 0; e < E_; ++e) cnt[lane][e] = 0;
  __syncthreads();
  for (int k = 0; k < CH; ++k) cnt[lane][e1[lane*CH + k]]++;
  __syncthreads();
  if (lane < E_) {
    int run = 0;
    for (int j = 0; j < 64; ++j) { int t = cnt[j][lane]; cnt[j][lane] = run; run += t; }
    tot1[lane] = run;                             // raw (pre-capacity) total
  }
  __syncthreads();
  for (int k = 0; k < CH; ++k) {
    int s = lane*CH + k;
    int e = e1[s];
    int p = cnt[lane][e]++;
    int tg = h*S_ + s;
    if (p < CAP) { tokP1[tg] = p; slotTok[e*MR + h*CAP + p] = tg; }
    else         { tokP1[tg] = -1; }
  }
  __syncthreads();
  // choice 2 (offset by raw tot1)
  #pragma unroll
  for (int e = 0; e < E_; ++e) cnt[lane][e] = 0;
  __syncthreads();
  for (int k = 0; k < CH; ++k) cnt[lane][e2[lane*CH + k]]++;
  __syncthreads();
  if (lane < E_) {
    int run = tot1[lane];
    for (int j = 0; j < 64; ++j) { int t = cnt[j][lane]; cnt[j][lane] = run; run += t; }
  }
  __syncthreads();
  for (int k = 0; k < CH; ++k) {
    int s = lane*CH + k;
    int e = e2[s];
    int p = cnt[lane][e]++;
    int tg = h*S_ + s;
    if (p < CAP) { tokP2[tg] = p; slotTok[e*MR + h*CAP + p] = tg; }
    else         { tokP2[tg] = -1; }
  }
  __syncthreads();
  // gate renorm after capacity drops (den cancels softmax norm exactly)
  for (int k = 0; k < CH; ++k) {
    int tg = h*S_ + k*64 + lane;
    float g1 = (tokP1[tg] >= 0) ? tokG1[tg] : 0.f;
    float g2 = (tokP2[tg] >= 0) ? tokG2[tg] : 0.f;
    float den = fmaxf(g1 + g2, 1e-9f);
    tokG1[tg] = g1 / den;
    tokG2[tg] = g2 / den;
  }
}

// ---- 4) gather tokens -> A1 bf16 [E][MR][D_IN], XOR swizzle baked --------
__global__ __launch_bounds__(256)
void k_gather1(const float* __restrict__ x, const int* __restrict__ slotTok,
               unsigned short* __restrict__ A1) {
  int row = blockIdx.x;                // e*MR + r ; row&7 == r&7 (MR%8==0)
  int tok = slotTok[row];
  int t = threadIdx.x;
  int k = t*4;
  int ba = ((k & 63)*2) ^ ((row & 7) << 4);       // swizzle within 64-elem chunk
  char* dst = (char*)A1 + (size_t)row*(D_IN*2) + (size_t)(k >> 6)*128 + ba;
  u16x4 pk;
  if (tok >= 0) {
    int h = tok >> 11, s = tok & 2047;
    int bi = s >> 9, ni = s & 511;
    const float* xr = x + ((size_t)bi*SEQ + (size_t)h*NSUB + ni) * D_IN;
    f32x4 v = *(const f32x4*)(xr + k);
    pk.x = f2bf(v.x); pk.y = f2bf(v.y); pk.z = f2bf(v.z); pk.w = f2bf(v.w);
  } else {
    pk.x = 0; pk.y = 0; pk.z = 0; pk.w = 0;
  }
  *(u16x4*)dst = pk;
}

// ---- 5) GEMM: Out[e] = A[e] @ W[e] + bias[e]; A bf16 (swizzle-baked), W fp32
// 128x128 tile, BK=64, 4 waves, mfma_f32_16x16x32_bf16, fp32 accum, bf16 out
template<int K, int N>
__global__ __launch_bounds__(256, 2)
void k_gemm(const unsigned short* __restrict__ A, const float* __restrict__ W,
            const float* __restrict__ bias, unsigned short* __restrict__ Out) {
  const int NT = N / 128;
  int bid = blockIdx.x;
  int mt  = bid % MT;
  int rem = bid / MT;
  int nt  = rem % NT;
  int e   = rem / NT;
  const char*  Ab = (const char*)A + ((size_t)e*MR + (size_t)mt*128) * (K*2);
  const float* We = W + (size_t)e*K*N + (size_t)nt*128;
  __shared__ unsigned short As[128*64];   // [row][k]  (swizzled bytes)
  __shared__ unsigned short Bs[128*64];   // [n][k]    (transposed, swizzled)
  int tid = threadIdx.x;
  int lane = tid & 63;
  int wid  = tid >> 6;
  int wr = wid >> 1, wc = wid & 1;
  f32x4 acc[4][4];
  #pragma unroll
  for (int i = 0; i < 4; ++i)
    #pragma unroll
    for (int j = 0; j < 4; ++j) acc[i][j] = (f32x4)0.f;

  // B-staging mapping: thread owns column bn, k-range [bkh, bkh+32)
  int bn  = tid & 127;
  int bkh = (tid >> 7) * 32;
  float bReg[32];
  u32x4 aReg[4];

  auto loadA = [&](int kt) {
    #pragma unroll
    for (int i = 0; i < 4; ++i) {
      int L = tid*16 + i*4096;
      aReg[i] = *(const u32x4*)(Ab + (size_t)(L >> 7)*(K*2) + (size_t)kt*128 + (L & 127));
    }
  };
  auto loadB = [&](int kt) {
    const float* p = We + (size_t)(kt*64 + bkh)*N + bn;
    #pragma unroll
    for (int q = 0; q < 32; ++q) bReg[q] = p[(size_t)q*N];
  };

  const int NKT = K/64;
  loadA(0); loadB(0);
  for (int kt = 0; kt < NKT; ++kt) {
    // write staged regs -> LDS
    #pragma unroll
    for (int i = 0; i < 4; ++i) {
      int L = tid*16 + i*4096;
      *(u32x4*)((char*)As + L) = aReg[i];
    }
    #pragma unroll
    for (int q = 0; q < 8; ++q) {
      u16x4 pk;
      pk.x = f2bf(bReg[q*4+0]); pk.y = f2bf(bReg[q*4+1]);
      pk.z = f2bf(bReg[q*4+2]); pk.w = f2bf(bReg[q*4+3]);
      int k0 = bkh + q*4;
      int ba = (bn*128 + k0*2) ^ ((bn & 7) << 4);
      *(u16x4*)((char*)Bs + ba) = pk;
    }
    __syncthreads();
    if (kt + 1 < NKT) { loadA(kt+1); loadB(kt+1); }   // prefetch overlaps MFMA
    #pragma unroll
    for (int kk = 0; kk < 2; ++kk) {
      s16x8 afr[4], bfr[4];
      int kx = kk*32 + (lane >> 4)*8;
      #pragma unroll
      for (int i = 0; i < 4; ++i) {
        int row = wr*64 + i*16 + (lane & 15);
        afr[i] = *(const s16x8*)((const char*)As + ((row*128 + kx*2) ^ ((row & 7) << 4)));
        int nr  = wc*64 + i*16 + (lane & 15);
        bfr[i] = *(const s16x8*)((const char*)Bs + ((nr*128 + kx*2) ^ ((nr & 7) << 4)));
      }
      #pragma unroll
      for (int i = 0; i < 4; ++i)
        #pragma unroll
        for (int j = 0; j < 4; ++j)
          acc[i][j] = __builtin_amdgcn_mfma_f32_16x16x32_bf16(afr[i], bfr[j], acc[i][j], 0, 0, 0);
    }
    __syncthreads();
  }
  // epilogue: +bias, bf16 store (plain layout)
  #pragma unroll
  for (int j = 0; j < 4; ++j) {
    int col = nt*128 + wc*64 + j*16 + (lane & 15);
    float bv = bias[(size_t)e*N + col];
    #pragma unroll
    for (int i = 0; i < 4; ++i) {
      int rowb = mt*128 + wr*64 + i*16 + (lane >> 4)*4;
      #pragma unroll
      for (int r = 0; r < 4; ++r) {
        float v = acc[i][j][r] + bv;
        Out[(size_t)e*MR*N + (size_t)(rowb + r)*N + col] = f2bf(v);
      }
    }
  }
}

// ---- 6) zero A2 rows with no token (incl. pad rows) ----------------------
__global__ __launch_bounds__(256)
void k_zero_empty(const int* __restrict__ slotTok, unsigned short* __restrict__ A2) {
  int row = blockIdx.x;
  if (slotTok[row] >= 0) return;
  u32x4 z = (u32x4)0u;
  char* base = (char*)A2 + (size_t)row*(D_HID*2) + threadIdx.x*32;
  *(u32x4*)base = z;
  *(u32x4*)(base + 16) = z;
}

// ---- 7) combine g1*H1[r1]+g2*H1[r2] -> LN -> ReLU -> redispatch into A2 --
__global__ __launch_bounds__(256)
void k_combine_ln(const unsigned short* __restrict__ H1,
                  const int* __restrict__ tokE1, const int* __restrict__ tokE2,
                  const int* __restrict__ tokP1, const int* __restrict__ tokP2,
                  const float* __restrict__ tokG1, const float* __restrict__ tokG2,
                  const float* __restrict__ lnw, const float* __restrict__ lnb,
                  unsigned short* __restrict__ A2) {
  int tg = blockIdx.x;
  int h = tg >> 11;
  int p1 = tokP1[tg], p2 = tokP2[tg];
  if (p1 < 0 && p2 < 0) return;                       // no slots; out=0 later
  float g1 = tokG1[tg], g2 = tokG2[tg];
  long r1 = (p1 >= 0) ? ((long)tokE1[tg]*MR + h*CAP + p1) : -1;
  long r2 = (p2 >= 0) ? ((long)tokE2[tg]*MR + h*CAP + p2) : -1;
  int t = threadIdx.x;
  float v[16];
  float sum = 0.f, sq = 0.f;
  #pragma unroll
  for (int u = 0; u < 4; ++u) {
    int f = u*1024 + t*4;
    float a0 = 0.f, a1 = 0.f, a2 = 0.f, a3 = 0.f;
    if (r1 >= 0) {
      u16x4 q = *(const u16x4*)(H1 + (size_t)r1*D_HID + f);
      a0 += g1*bf2f(q.x); a1 += g1*bf2f(q.y); a2 += g1*bf2f(q.z); a3 += g1*bf2f(q.w);
    }
    if (r2 >= 0) {
      u16x4 q = *(const u16x4*)(H1 + (size_t)r2*D_HID + f);
      a0 += g2*bf2f(q.x); a1 += g2*bf2f(q.y); a2 += g2*bf2f(q.z); a3 += g2*bf2f(q.w);
    }
    v[u*4+0] = a0; v[u*4+1] = a1; v[u*4+2] = a2; v[u*4+3] = a3;
    sum += a0 + a1 + a2 + a3;
    sq  += a0*a0 + a1*a1 + a2*a2 + a3*a3;
  }
  #pragma unroll
  for (int o = 32; o; o >>= 1) { sum += __shfl_xor(sum, o); sq += __shfl_xor(sq, o); }
  __shared__ float redA[4], redB[4];
  int wid = t >> 6;
  if ((t & 63) == 0) { redA[wid] = sum; redB[wid] = sq; }
  __syncthreads();
  float S = redA[0] + redA[1] + redA[2] + redA[3];
  float Q = redB[0] + redB[1] + redB[2] + redB[3];
  float m = S * (1.f / D_HID);
  float var = Q * (1.f / D_HID) - m*m;
  float rs = rsqrtf(var + 1e-6f);
  #pragma unroll
  for (int u = 0; u < 4; ++u) {
    int f = u*1024 + t*4;
    u16x4 pk;
    float y0 = fmaxf((v[u*4+0]-m)*rs*lnw[h*D_HID+f+0] + lnb[h*D_HID+f+0], 0.f);
    float y1 = fmaxf((v[u*4+1]-m)*rs*lnw[h*D_HID+f+1] + lnb[h*D_HID+f+1], 0.f);
    float y2 = fmaxf((v[u*4+2]-m)*rs*lnw[h*D_HID+f+2] + lnb[h*D_HID+f+2], 0.f);
    float y3 = fmaxf((v[u*4+3]-m)*rs*lnw[h*D_HID+f+3] + lnb[h*D_HID+f+3], 0.f);
    pk.x = f2bf(y0); pk.y = f2bf(y1); pk.z = f2bf(y2); pk.w = f2bf(y3);
    int chunk = f >> 6;
    int ob = (f & 63)*2;
    if (r1 >= 0)
      *(u16x4*)((char*)A2 + (size_t)r1*(D_HID*2) + (size_t)chunk*128 + (ob ^ (((int)r1 & 7) << 4))) = pk;
    if (r2 >= 0)
      *(u16x4*)((char*)A2 + (size_t)r2*(D_HID*2) + (size_t)chunk*128 + (ob ^ (((int)r2 & 7) << 4))) = pk;
  }
}

// ---- 8) final combine + residual + LayerNorm -----------------------------
__global__ __launch_bounds__(256)
void k_final(const unsigned short* __restrict__ H2, const float* __restrict__ x,
             const int* __restrict__ tokE1, const int* __restrict__ tokE2,
             const int* __restrict__ tokP1, const int* __restrict__ tokP2,
             const float* __restrict__ tokG1, const float* __restrict__ tokG2,
             const float* __restrict__ lnw, const float* __restrict__ lnb,
             float* __restrict__ out) {
  int tg = blockIdx.x;
  int h = tg >> 11, s = tg & 2047;
  int bi = s >> 9, ni = s & 511;
  size_t xoff = ((size_t)bi*SEQ + (size_t)h*NSUB + ni) * D_IN;
  int p1 = tokP1[tg], p2 = tokP2[tg];
  float g1 = tokG1[tg], g2 = tokG2[tg];
  int t = threadIdx.x;
  int f = t*4;
  f32x4 xv = *(const f32x4*)(x + xoff + f);
  float v0 = xv.x, v1 = xv.y, v2 = xv.z, v3 = xv.w;
  if (p1 >= 0) {
    size_t r1 = (size_t)tokE1[tg]*MR + h*CAP + p1;
    u16x4 q = *(const u16x4*)(H2 + r1*D_IN + f);
    v0 += g1*bf2f(q.x); v1 += g1*bf2f(q.y); v2 += g1*bf2f(q.z); v3 += g1*bf2f(q.w);
  }
  if (p2 >= 0) {
    size_t r2 = (size_t)tokE2[tg]*MR + h*CAP + p2;
    u16x4 q = *(const u16x4*)(H2 + r2*D_IN + f);
    v0 += g2*bf2f(q.x); v1 += g2*bf2f(q.y); v2 += g2*bf2f(q.z); v3 += g2*bf2f(q.w);
  }
  float sum = v0+v1+v2+v3, sq = v0*v0+v1*v1+v2*v2+v3*v3;
  #pragma unroll
  for (int o = 32; o; o >>= 1) { sum += __shfl_xor(sum, o); sq += __shfl_xor(sq, o); }
  __shared__ float redA[4], redB[4];
  int wid = t >> 6;
  if ((t & 63) == 0) { redA[wid] = sum; redB[wid] = sq; }
  __syncthreads();
  float S = redA[0] + redA[1] + redA[2] + redA[3];
  float Q = redB[0] + redB[1] + redB[2] + redB[3];
  float m = S * (1.f / D_IN);
  float var = Q * (1.f / D_IN) - m*m;
  float rs = rsqrtf(var + 1e-6f);
  f32x4 res;
  res.x = (v0 - m)*rs*lnw[f+0] + lnb[f+0];
  res.y = (v1 - m)*rs*lnw[f+1] + lnb[f+1];
  res.z = (v2 - m)*rs*lnw[f+2] + lnb[f+2];
  res.w = (v3 - m)*rs*lnw[f+3] + lnb[f+3];
  *(f32x4*)(out + xoff + f) = res;
}

// ---- launcher ------------------------------------------------------------
extern "C" void kernel_launch(void* const* d_in, const int* in_sizes, int n_in,
                              void* d_out, int out_size, void* d_ws, size_t ws_size,
                              hipStream_t stream) {
  const float* x    = (const float*)d_in[0];
  const float* Wg   = (const float*)d_in[1];
  const float* W1   = (const float*)d_in[2];
  const float* b1   = (const float*)d_in[3];
  const float* W2   = (const float*)d_in[4];
  const float* b2   = (const float*)d_in[5];
  const float* lnhw = (const float*)d_in[6];
  const float* lnhb = (const float*)d_in[7];
  const float* lnow = (const float*)d_in[8];
  const float* lnob = (const float*)d_in[9];
  float* out = (float*)d_out;
  (void)in_sizes; (void)n_in; (void)out_size; (void)ws_size;

  char* ws = (char*)d_ws;
  size_t off = 0;
  auto take = [&](size_t bytes) -> char* {
    char* p = ws + off;
    off += (bytes + 255) & ~(size_t)255;
    return p;
  };
  int*   tokE1 = (int*)take(NTOKG*sizeof(int));
  int*   tokE2 = (int*)take(NTOKG*sizeof(int));
  int*   tokP1 = (int*)take(NTOKG*sizeof(int));
  int*   tokP2 = (int*)take(NTOKG*sizeof(int));
  float* tokG1 = (float*)take(NTOKG*sizeof(float));
  float* tokG2 = (float*)take(NTOKG*sizeof(float));
  int*   slotTok = (int*)take((size_t)E_*MR*sizeof(int));
  unsigned short* A1 = (unsigned short*)take((size_t)E_*MR*D_IN*2);   //  37.7 MB
  unsigned short* H1 = (unsigned short*)take((size_t)E_*MR*D_HID*2);  // 151.0 MB
  unsigned short* A2 = (unsigned short*)take((size_t)E_*MR*D_HID*2);  // 151.0 MB
  unsigned short* H2 = (unsigned short*)take((size_t)E_*MR*D_IN*2);   //  37.7 MB

  k_init_slots<<<dim3(E_*MR/256), dim3(256), 0, stream>>>(slotTok);
  k_gating<<<dim3(NTOKG), dim3(64), 0, stream>>>(x, Wg, tokE1, tokE2, tokG1, tokG2);
  k_scan<<<dim3(HGRP), dim3(64), 0, stream>>>(tokE1, tokE2, tokG1, tokG2, tokP1, tokP2, slotTok);
  k_gather1<<<dim3(E_*MR), dim3(256), 0, stream>>>(x, slotTok, A1);
  k_gemm<D_IN, D_HID><<<dim3(E_*(D_HID/128)*MT), dim3(256), 0, stream>>>(A1, W1, b1, H1);
  k_zero_empty<<<dim3(E_*MR), dim3(256), 0, stream>>>(slotTok, A2);
  k_combine_ln<<<dim3(NTOKG), dim3(256), 0, stream>>>(H1, tokE1, tokE2, tokP1, tokP2,
                                                      tokG1, tokG2, lnhw, lnhb, A2);
  k_gemm<D_HID, D_IN><<<dim3(E_*(D_IN/128)*MT), dim3(256), 0, stream>>>(A2, W2, b2, H2);
  k_final<<<dim3(NTOKG), dim3(256), 0, stream>>>(H2, x, tokE1, tokE2, tokP1, tokP2,
                                                 tokG1, tokG2, lnow, lnob, out);
}

// Round 2
// 812.383 us; speedup vs baseline: 1.3601x; 1.3601x over previous
//
#include <hip/hip_runtime.h>
#include <cstdint>
#include <cstddef>

// ---- fixed problem shape (from setup_inputs) ------------------------------
#define E_      24          // experts
#define D_IN    1024
#define D_HID   4096
#define HGRP    4           // groups (H)
#define BSZ     4
#define SEQ     2048
#define NSUB    512         // seq / HGRP
#define S_      2048        // tokens per group = BSZ*NSUB
#define NTOKG   8192        // HGRP * S_
#define CAP     171         // ceil(2*S_/E_)
#define MR      768         // per-expert rows, 4*CAP=684 padded to 3*256
#define MTILE   3           // M tiles of 256

typedef __attribute__((ext_vector_type(4))) float          f32x4;
typedef __attribute__((ext_vector_type(2))) float          f32x2;
typedef __attribute__((ext_vector_type(4))) unsigned short u16x4;
typedef __attribute__((ext_vector_type(8))) unsigned short u16x8;
typedef __attribute__((ext_vector_type(4))) unsigned int   u32x4;
typedef __attribute__((ext_vector_type(8))) short          s16x8;

__device__ __forceinline__ unsigned short f2bf(float f) {   // RNE f32->bf16
  unsigned int u = __float_as_uint(f);
  u += 0x7fffu + ((u >> 16) & 1u);
  return (unsigned short)(u >> 16);
}
__device__ __forceinline__ float bf2f(unsigned short v) {
  return __uint_as_float(((unsigned int)v) << 16);
}

// ---- 1) gating: logits = x_row @ Wg, softmax, top-2 (first-max ties) -----
__global__ __launch_bounds__(64)
void k_gating(const float* __restrict__ x, const float* __restrict__ Wg,
              int* __restrict__ tokE1, int* __restrict__ tokE2,
              float* __restrict__ tokG1, float* __restrict__ tokG2) {
  int tg = blockIdx.x;                 // h*S_ + s
  int h = tg >> 11, s = tg & 2047;
  int bi = s >> 9, ni = s & 511;
  const float* xr = x + ((size_t)bi*SEQ + (size_t)h*NSUB + ni) * D_IN;
  int lane = threadIdx.x;
  float acc[E_];
  #pragma unroll
  for (int e = 0; e < E_; ++e) acc[e] = 0.f;
  #pragma unroll
  for (int it = 0; it < D_IN/256; ++it) {
    f32x4 xv = *(const f32x4*)(xr + it*256 + lane*4);
    #pragma unroll
    for (int j = 0; j < 4; ++j) {
      float xs = xv[j];
      const float* wrow = Wg + (size_t)(it*256 + lane*4 + j) * E_;
      #pragma unroll
      for (int e = 0; e < E_; ++e) acc[e] += xs * wrow[e];
    }
  }
  #pragma unroll
  for (int e = 0; e < E_; ++e) {
    float v = acc[e];
    v += __shfl_xor(v, 32); v += __shfl_xor(v, 16); v += __shfl_xor(v, 8);
    v += __shfl_xor(v, 4);  v += __shfl_xor(v, 2);  v += __shfl_xor(v, 1);
    acc[e] = v;
  }
  if (lane == 0) {
    float mx = acc[0];
    #pragma unroll
    for (int e = 1; e < E_; ++e) mx = fmaxf(mx, acc[e]);
    float den = 0.f;
    #pragma unroll
    for (int e = 0; e < E_; ++e) den += expf(acc[e] - mx);
    int i1 = 0; float v1 = acc[0];
    #pragma unroll
    for (int e = 1; e < E_; ++e) if (acc[e] > v1) { v1 = acc[e]; i1 = e; }  // first max
    int i2 = -1; float v2 = -3.4e38f;
    #pragma unroll
    for (int e = 0; e < E_; ++e) if (e != i1 && acc[e] > v2) { v2 = acc[e]; i2 = e; }
    tokE1[tg] = i1; tokE2[tg] = i2;
    tokG1[tg] = expf(v1 - mx) / den;   // raw softmax probs; renorm after drops
    tokG2[tg] = expf(v2 - mx) / den;
  }
}

// ---- 2) slot map init ----------------------------------------------------
__global__ void k_init_slots(int* __restrict__ slotTok) {
  slotTok[blockIdx.x*256 + threadIdx.x] = -1;
}

// ---- 3) capacity scan: exact cumsum order, loc2 offset by RAW top1 totals
__global__ __launch_bounds__(64)
void k_scan(const int* __restrict__ tokE1, const int* __restrict__ tokE2,
            float* __restrict__ tokG1, float* __restrict__ tokG2,
            int* __restrict__ tokP1, int* __restrict__ tokP2,
            int* __restrict__ slotTok) {
  int h = blockIdx.x;
  int lane = threadIdx.x;
  __shared__ int cnt[64][E_];
  __shared__ int tot1[E_];
  const int CH = S_/64;                           // 32 tokens per lane chunk
  const int* e1 = tokE1 + h*S_;
  const int* e2 = tokE2 + h*S_;
  // choice 1
  #pragma unroll
  for (int e = 0; e < E_; ++e) cnt[lane][e] = 0;
  __syncthreads();
  for (int k = 0; k < CH; ++k) cnt[lane][e1[lane*CH + k]]++;
  __syncthreads();
  if (lane < E_) {
    int run = 0;
    for (int j = 0; j < 64; ++j) { int t = cnt[j][lane]; cnt[j][lane] = run; run += t; }
    tot1[lane] = run;                             // raw (pre-capacity) total
  }
  __syncthreads();
  for (int k = 0; k < CH; ++k) {
    int s = lane*CH + k;
    int e = e1[s];
    int p = cnt[lane][e]++;
    int tg = h*S_ + s;
    if (p < CAP) { tokP1[tg] = p; slotTok[e*MR + h*CAP + p] = tg; }
    else         { tokP1[tg] = -1; }
  }
  __syncthreads();
  // choice 2 (offset by raw tot1)
  #pragma unroll
  for (int e = 0; e < E_; ++e) cnt[lane][e] = 0;
  __syncthreads();
  for (int k = 0; k < CH; ++k) cnt[lane][e2[lane*CH + k]]++;
  __syncthreads();
  if (lane < E_) {
    int run = tot1[lane];
    for (int j = 0; j < 64; ++j) { int t = cnt[j][lane]; cnt[j][lane] = run; run += t; }
  }
  __syncthreads();
  for (int k = 0; k < CH; ++k) {
    int s = lane*CH + k;
    int e = e2[s];
    int p = cnt[lane][e]++;
    int tg = h*S_ + s;
    if (p < CAP) { tokP2[tg] = p; slotTok[e*MR + h*CAP + p] = tg; }
    else         { tokP2[tg] = -1; }
  }
  __syncthreads();
  // gate renorm after capacity drops (den cancels softmax norm exactly)
  for (int k = 0; k < CH; ++k) {
    int tg = h*S_ + k*64 + lane;
    float g1 = (tokP1[tg] >= 0) ? tokG1[tg] : 0.f;
    float g2 = (tokP2[tg] >= 0) ? tokG2[tg] : 0.f;
    float den = fmaxf(g1 + g2, 1e-9f);
    tokG1[tg] = g1 / den;
    tokG2[tg] = g2 / den;
  }
}

// ---- 4) gather tokens -> A1 bf16 [E][MR][D_IN], XOR swizzle baked --------
__global__ __launch_bounds__(256)
void k_gather1(const float* __restrict__ x, const int* __restrict__ slotTok,
               unsigned short* __restrict__ A1) {
  int row = blockIdx.x;                // e*MR + r ; row&7 == r&7 (MR%8==0)
  int tok = slotTok[row];
  int t = threadIdx.x;
  int k = t*4;
  int ba = ((k & 63)*2) ^ ((row & 7) << 4);       // swizzle within 64-elem chunk
  char* dst = (char*)A1 + (size_t)row*(D_IN*2) + (size_t)(k >> 6)*128 + ba;
  u16x4 pk;
  if (tok >= 0) {
    int h = tok >> 11, s = tok & 2047;
    int bi = s >> 9, ni = s & 511;
    const float* xr = x + ((size_t)bi*SEQ + (size_t)h*NSUB + ni) * D_IN;
    f32x4 v = *(const f32x4*)(xr + k);
    pk.x = f2bf(v.x); pk.y = f2bf(v.y); pk.z = f2bf(v.z); pk.w = f2bf(v.w);
  } else {
    pk.x = 0; pk.y = 0; pk.z = 0; pk.w = 0;
  }
  *(u16x4*)dst = pk;
}

// ---- 5) GEMM: Out[e] = A[e] @ W[e] + bias[e]
// 256x128 tile, BK=64, 8 waves (512 thr), mfma_f32_16x16x32_bf16.
// A bf16 with XOR swizzle baked in global -> staged via global_load_lds x16.
// W fp32 [K][N] -> float2 reg loads (prefetched across MFMA), bf16 pack,
// transposed+swizzled ds_write_b128 into Bs[n][k].
template<int K, int N>
__global__ __launch_bounds__(512, 4)
void k_gemm(const unsigned short* __restrict__ A, const float* __restrict__ W,
            const float* __restrict__ bias, unsigned short* __restrict__ Out) {
  const int NT = N / 128;
  // XCD-bijective swizzle: consecutive logical blocks -> same XCD (gridDim%8==0)
  int cpx = gridDim.x >> 3;
  int lb = blockIdx.x;
  int bid = (lb & 7) * cpx + (lb >> 3);
  int mt  = bid % MTILE;                 // mt innermost: 3 blocks share a W panel
  int rem = bid / MTILE;
  int nt  = rem % NT;
  int e   = rem / NT;

  const char*  Ab = (const char*)A + ((size_t)e*MR + (size_t)mt*256) * (K*2);
  const float* We = W + (size_t)e*K*N + (size_t)nt*128;

  __shared__ unsigned short As[256*64];   // 32 KB  [row][k] swizzled
  __shared__ unsigned short Bs[128*64];   // 16 KB  [n][k]   swizzled
  int tid  = threadIdx.x;
  int lane = tid & 63;
  int wid  = tid >> 6;
  int wr = wid >> 1, wc = wid & 1;        // wave -> 64x64 output sub-tile

  f32x4 acc[4][4];
  #pragma unroll
  for (int i = 0; i < 4; ++i)
    #pragma unroll
    for (int j = 0; j < 4; ++j) acc[i][j] = (f32x4)0.f;

  // B staging: thread owns cols {bn0, bn0+1}, k-range [bkh, bkh+8)
  int bn0 = (tid & 63) * 2;
  int bkh = (tid >> 6) * 8;
  f32x2 bPre[8];

  auto loadB = [&](int kt) {
    const float* p = We + (size_t)(kt*64 + bkh)*N + bn0;
    #pragma unroll
    for (int q = 0; q < 8; ++q) bPre[q] = *(const f32x2*)(p + (size_t)q*N);
  };
  auto storeB = [&]() {
    u16x8 c0, c1;
    #pragma unroll
    for (int q = 0; q < 8; ++q) { c0[q] = f2bf(bPre[q].x); c1[q] = f2bf(bPre[q].y); }
    int r0 = bn0, r1 = bn0 + 1;
    *(u16x8*)((char*)Bs + r0*128 + ((bkh*2) ^ ((r0 & 7) << 4))) = c0;
    *(u16x8*)((char*)Bs + r1*128 + ((bkh*2) ^ ((r1 & 7) << 4))) = c1;
  };
  auto stageA = [&](int kt) {           // async global->LDS, 16B/lane, linear dest
    #pragma unroll
    for (int i = 0; i < 4; ++i) {
      int L = i*8192 + tid*16;
      const char* src = Ab + (size_t)(L >> 7)*(K*2) + (size_t)kt*128 + (L & 127);
      __builtin_amdgcn_global_load_lds(
          (const __attribute__((address_space(1))) void*)src,
          (__attribute__((address_space(3))) void*)((char*)As + L),
          16, 0, 0);
    }
  };

  const int NKT = K / 64;
  loadB(0);
  for (int kt = 0; kt < NKT; ++kt) {
    __syncthreads();                     // prev compute done; LDS reusable
    stageA(kt);
    storeB();
    __syncthreads();                     // drains vmcnt (gload_lds) + lgkm
    if (kt + 1 < NKT) loadB(kt + 1);     // reg prefetch overlaps MFMA
    #pragma unroll
    for (int kk = 0; kk < 2; ++kk) {
      s16x8 afr[4], bfr[4];
      int kx2 = (kk*32 + (lane >> 4)*8) * 2;   // byte offset of k within row
      #pragma unroll
      for (int i = 0; i < 4; ++i) {
        int row = wr*64 + i*16 + (lane & 15);
        afr[i] = *(const s16x8*)((const char*)As + row*128 + (kx2 ^ ((row & 7) << 4)));
        int col = wc*64 + i*16 + (lane & 15);
        bfr[i] = *(const s16x8*)((const char*)Bs + col*128 + (kx2 ^ ((col & 7) << 4)));
      }
      #pragma unroll
      for (int i = 0; i < 4; ++i)
        #pragma unroll
        for (int j = 0; j < 4; ++j)
          acc[i][j] = __builtin_amdgcn_mfma_f32_16x16x32_bf16(afr[i], bfr[j], acc[i][j], 0, 0, 0);
    }
  }
  // epilogue: +bias, bf16 store (plain layout)
  #pragma unroll
  for (int j = 0; j < 4; ++j) {
    int col = nt*128 + wc*64 + j*16 + (lane & 15);
    float bv = bias[(size_t)e*N + col];
    #pragma unroll
    for (int i = 0; i < 4; ++i) {
      int rowb = mt*256 + wr*64 + i*16 + (lane >> 4)*4;
      #pragma unroll
      for (int r = 0; r < 4; ++r) {
        float v = acc[i][j][r] + bv;
        Out[(size_t)e*MR*N + (size_t)(rowb + r)*N + col] = f2bf(v);
      }
    }
  }
}

// ---- 6) zero A2 rows with no token (incl. pad rows) ----------------------
__global__ __launch_bounds__(256)
void k_zero_empty(const int* __restrict__ slotTok, unsigned short* __restrict__ A2) {
  int row = blockIdx.x;
  if (slotTok[row] >= 0) return;
  u32x4 z = (u32x4)0u;
  char* base = (char*)A2 + (size_t)row*(D_HID*2) + threadIdx.x*32;
  *(u32x4*)base = z;
  *(u32x4*)(base + 16) = z;
}

// ---- 7) combine g1*H1[r1]+g2*H1[r2] -> LN -> ReLU -> redispatch into A2 --
__global__ __launch_bounds__(256)
void k_combine_ln(const unsigned short* __restrict__ H1,
                  const int* __restrict__ tokE1, const int* __restrict__ tokE2,
                  const int* __restrict__ tokP1, const int* __restrict__ tokP2,
                  const float* __restrict__ tokG1, const float* __restrict__ tokG2,
                  const float* __restrict__ lnw, const float* __restrict__ lnb,
                  unsigned short* __restrict__ A2) {
  int tg = blockIdx.x;
  int h = tg >> 11;
  int p1 = tokP1[tg], p2 = tokP2[tg];
  if (p1 < 0 && p2 < 0) return;                       // no slots; rows zeroed
  float g1 = tokG1[tg], g2 = tokG2[tg];
  long r1 = (p1 >= 0) ? ((long)tokE1[tg]*MR + h*CAP + p1) : -1;
  long r2 = (p2 >= 0) ? ((long)tokE2[tg]*MR + h*CAP + p2) : -1;
  int t = threadIdx.x;
  float v[16];
  float sum = 0.f, sq = 0.f;
  #pragma unroll
  for (int u = 0; u < 4; ++u) {
    int f = u*1024 + t*4;
    float a0 = 0.f, a1 = 0.f, a2 = 0.f, a3 = 0.f;
    if (r1 >= 0) {
      u16x4 q = *(const u16x4*)(H1 + (size_t)r1*D_HID + f);
      a0 += g1*bf2f(q.x); a1 += g1*bf2f(q.y); a2 += g1*bf2f(q.z); a3 += g1*bf2f(q.w);
    }
    if (r2 >= 0) {
      u16x4 q = *(const u16x4*)(H1 + (size_t)r2*D_HID + f);
      a0 += g2*bf2f(q.x); a1 += g2*bf2f(q.y); a2 += g2*bf2f(q.z); a3 += g2*bf2f(q.w);
    }
    v[u*4+0] = a0; v[u*4+1] = a1; v[u*4+2] = a2; v[u*4+3] = a3;
    sum += a0 + a1 + a2 + a3;
    sq  += a0*a0 + a1*a1 + a2*a2 + a3*a3;
  }
  #pragma unroll
  for (int o = 32; o; o >>= 1) { sum += __shfl_xor(sum, o); sq += __shfl_xor(sq, o); }
  __shared__ float redA[4], redB[4];
  int wid = t >> 6;
  if ((t & 63) == 0) { redA[wid] = sum; redB[wid] = sq; }
  __syncthreads();
  float S = redA[0] + redA[1] + redA[2] + redA[3];
  float Q = redB[0] + redB[1] + redB[2] + redB[3];
  float m = S * (1.f / D_HID);
  float var = Q * (1.f / D_HID) - m*m;
  float rs = rsqrtf(var + 1e-6f);
  #pragma unroll
  for (int u = 0; u < 4; ++u) {
    int f = u*1024 + t*4;
    u16x4 pk;
    float y0 = fmaxf((v[u*4+0]-m)*rs*lnw[h*D_HID+f+0] + lnb[h*D_HID+f+0], 0.f);
    float y1 = fmaxf((v[u*4+1]-m)*rs*lnw[h*D_HID+f+1] + lnb[h*D_HID+f+1], 0.f);
    float y2 = fmaxf((v[u*4+2]-m)*rs*lnw[h*D_HID+f+2] + lnb[h*D_HID+f+2], 0.f);
    float y3 = fmaxf((v[u*4+3]-m)*rs*lnw[h*D_HID+f+3] + lnb[h*D_HID+f+3], 0.f);
    pk.x = f2bf(y0); pk.y = f2bf(y1); pk.z = f2bf(y2); pk.w = f2bf(y3);
    int chunk = f >> 6;
    int ob = (f & 63)*2;
    if (r1 >= 0)
      *(u16x4*)((char*)A2 + (size_t)r1*(D_HID*2) + (size_t)chunk*128 + (ob ^ (((int)r1 & 7) << 4))) = pk;
    if (r2 >= 0)
      *(u16x4*)((char*)A2 + (size_t)r2*(D_HID*2) + (size_t)chunk*128 + (ob ^ (((int)r2 & 7) << 4))) = pk;
  }
}

// ---- 8) final combine + residual + LayerNorm -----------------------------
__global__ __launch_bounds__(256)
void k_final(const unsigned short* __restrict__ H2, const float* __restrict__ x,
             const int* __restrict__ tokE1, const int* __restrict__ tokE2,
             const int* __restrict__ tokP1, const int* __restrict__ tokP2,
             const float* __restrict__ tokG1, const float* __restrict__ tokG2,
             const float* __restrict__ lnw, const float* __restrict__ lnb,
             float* __restrict__ out) {
  int tg = blockIdx.x;
  int h = tg >> 11, s = tg & 2047;
  int bi = s >> 9, ni = s & 511;
  size_t xoff = ((size_t)bi*SEQ + (size_t)h*NSUB + ni) * D_IN;
  int p1 = tokP1[tg], p2 = tokP2[tg];
  float g1 = tokG1[tg], g2 = tokG2[tg];
  int t = threadIdx.x;
  int f = t*4;
  f32x4 xv = *(const f32x4*)(x + xoff + f);
  float v0 = xv.x, v1 = xv.y, v2 = xv.z, v3 = xv.w;
  if (p1 >= 0) {
    size_t r1 = (size_t)tokE1[tg]*MR + h*CAP + p1;
    u16x4 q = *(const u16x4*)(H2 + r1*D_IN + f);
    v0 += g1*bf2f(q.x); v1 += g1*bf2f(q.y); v2 += g1*bf2f(q.z); v3 += g1*bf2f(q.w);
  }
  if (p2 >= 0) {
    size_t r2 = (size_t)tokE2[tg]*MR + h*CAP + p2;
    u16x4 q = *(const u16x4*)(H2 + r2*D_IN + f);
    v0 += g2*bf2f(q.x); v1 += g2*bf2f(q.y); v2 += g2*bf2f(q.z); v3 += g2*bf2f(q.w);
  }
  float sum = v0+v1+v2+v3, sq = v0*v0+v1*v1+v2*v2+v3*v3;
  #pragma unroll
  for (int o = 32; o; o >>= 1) { sum += __shfl_xor(sum, o); sq += __shfl_xor(sq, o); }
  __shared__ float redA[4], redB[4];
  int wid = t >> 6;
  if ((t & 63) == 0) { redA[wid] = sum; redB[wid] = sq; }
  __syncthreads();
  float S = redA[0] + redA[1] + redA[2] + redA[3];
  float Q = redB[0] + redB[1] + redB[2] + redB[3];
  float m = S * (1.f / D_IN);
  float var = Q * (1.f / D_IN) - m*m;
  float rs = rsqrtf(var + 1e-6f);
  f32x4 res;
  res.x = (v0 - m)*rs*lnw[f+0] + lnb[f+0];
  res.y = (v1 - m)*rs*lnw[f+1] + lnb[f+1];
  res.z = (v2 - m)*rs*lnw[f+2] + lnb[f+2];
  res.w = (v3 - m)*rs*lnw[f+3] + lnb[f+3];
  *(f32x4*)(out + xoff + f) = res;
}

// ---- launcher ------------------------------------------------------------
extern "C" void kernel_launch(void* const* d_in, const int* in_sizes, int n_in,
                              void* d_out, int out_size, void* d_ws, size_t ws_size,
                              hipStream_t stream) {
  const float* x    = (const float*)d_in[0];
  const float* Wg   = (const float*)d_in[1];
  const float* W1   = (const float*)d_in[2];
  const float* b1   = (const float*)d_in[3];
  const float* W2   = (const float*)d_in[4];
  const float* b2   = (const float*)d_in[5];
  const float* lnhw = (const float*)d_in[6];
  const float* lnhb = (const float*)d_in[7];
  const float* lnow = (const float*)d_in[8];
  const float* lnob = (const float*)d_in[9];
  float* out = (float*)d_out;
  (void)in_sizes; (void)n_in; (void)out_size; (void)ws_size;

  char* ws = (char*)d_ws;
  size_t off = 0;
  auto take = [&](size_t bytes) -> char* {
    char* p = ws + off;
    off += (bytes + 255) & ~(size_t)255;
    return p;
  };
  int*   tokE1 = (int*)take(NTOKG*sizeof(int));
  int*   tokE2 = (int*)take(NTOKG*sizeof(int));
  int*   tokP1 = (int*)take(NTOKG*sizeof(int));
  int*   tokP2 = (int*)take(NTOKG*sizeof(int));
  float* tokG1 = (float*)take(NTOKG*sizeof(float));
  float* tokG2 = (float*)take(NTOKG*sizeof(float));
  int*   slotTok = (int*)take((size_t)E_*MR*sizeof(int));
  unsigned short* A1 = (unsigned short*)take((size_t)E_*MR*D_IN*2);   //  37.7 MB
  unsigned short* H1 = (unsigned short*)take((size_t)E_*MR*D_HID*2);  // 151.0 MB
  unsigned short* A2 = (unsigned short*)take((size_t)E_*MR*D_HID*2);  // 151.0 MB
  unsigned short* H2 = (unsigned short*)take((size_t)E_*MR*D_IN*2);   //  37.7 MB

  k_init_slots<<<dim3(E_*MR/256), dim3(256), 0, stream>>>(slotTok);
  k_gating<<<dim3(NTOKG), dim3(64), 0, stream>>>(x, Wg, tokE1, tokE2, tokG1, tokG2);
  k_scan<<<dim3(HGRP), dim3(64), 0, stream>>>(tokE1, tokE2, tokG1, tokG2, tokP1, tokP2, slotTok);
  k_gather1<<<dim3(E_*MR), dim3(256), 0, stream>>>(x, slotTok, A1);
  k_gemm<D_IN, D_HID><<<dim3(E_*(D_HID/128)*MTILE), dim3(512), 0, stream>>>(A1, W1, b1, H1);
  k_zero_empty<<<dim3(E_*MR), dim3(256), 0, stream>>>(slotTok, A2);
  k_combine_ln<<<dim3(NTOKG), dim3(256), 0, stream>>>(H1, tokE1, tokE2, tokP1, tokP2,
                                                      tokG1, tokG2, lnhw, lnhb, A2);
  k_gemm<D_HID, D_IN><<<dim3(E_*(D_IN/128)*MTILE), dim3(512), 0, stream>>>(A2, W2, b2, H2);
  k_final<<<dim3(NTOKG), dim3(256), 0, stream>>>(H2, x, tokE1, tokE2, tokP1, tokP2,
                                                 tokG1, tokG2, lnow, lnob, out);
}